// Round 7
// baseline (7471.535 us; speedup 1.0000x reference)
//
#include <hip/hip_runtime.h>

typedef _Float16 f16;
typedef __attribute__((ext_vector_type(8))) _Float16 f16x8;
typedef __attribute__((ext_vector_type(4))) _Float16 f16x4;
typedef __attribute__((ext_vector_type(4))) float f32x4;

#define T_STEPS 784
#define HDIM    512
#define COUT    10
#define NGROUP  64
#define XFRAG   16384                     // bytes per group per parity (16 frags x 1KB)
#define XHALF   (NGROUP * XFRAG)

#define WF_BYTES (512 * 1024)
#define XT_OFF   WF_BYTES
#define XT_BYTES (T_STEPS * 1024 * 2)     // f16 xt
#define X_OFF    (XT_OFF + XT_BYTES)
#define X_BYTES  (2 * XHALF)
#define FL_OFF   (X_OFF + X_BYTES)
#define FL_BYTES (NGROUP * 64)
#define WS_NEED  ((size_t)(FL_OFF + FL_BYTES))

#define MFMA16(a, b, c) __builtin_amdgcn_mfma_f32_16x16x32_f16((a), (b), (c), 0, 0, 0)

__device__ inline void gload_lds16(const void* g, void* l) {
    __builtin_amdgcn_global_load_lds(
        (const __attribute__((address_space(1))) unsigned int*)g,
        (__attribute__((address_space(3))) unsigned int*)l, 16, 0, 0);
}

// W_rec f32 -> fp16, frag-major: frag index f = o_tile*16+kk (o_tile = outcol/16):
//   Wf[f*512 + lane*8 + j] = W_rec[o_tile*16+(lane&15)][kk*32+(lane>>4)*8+j]
__global__ void cvt_w(const float* __restrict__ W, f16* __restrict__ Wf) {
    const int c  = blockIdx.x * 256 + threadIdx.x;
    const int l  = c & 63;
    const int kk = (c >> 6) & 15;
    const int ot = c >> 10;
    const int row = ot * 16 + (l & 15);
    const int col = kk * 32 + (l >> 4) * 8;
    const float* s = W + row * HDIM + col;
    f16* d = Wf + (size_t)c * 8;
#pragma unroll
    for (int j = 0; j < 8; ++j) d[j] = (f16)s[j];
}

// xh[t][b] = (f16) x[b][perm[t]]
__global__ void permute_x(const float* __restrict__ x, const int* __restrict__ perm,
                          f16* __restrict__ xh) {
    const int i = blockIdx.x * 256 + threadIdx.x;
    const int t = i >> 10, b = i & 1023;
    xh[i] = (f16)x[b * T_STEPS + perm[t]];
}

// ---------------- main: 4-CU groups, register-resident W, L3 h-exchange ----
// 256 WGs x 512 thr. WG = (group g = bid&63, part p = bid>>6). Group owns 16
// batch rows; part p owns outcols [p*128, p*128+128). Each wave holds W
// A-frags for its 16 outcols resident in 64 VGPRs -- W is NEVER re-streamed.
// Per step: spin on 4 group flags (device scope), stage 16KB h from global
// into LDS (global_load_lds), 16 MFMA, write own 4KB piece + release flag.
// h exchange buffers are double-buffered by step parity (skew<=1 proven safe).
__global__ __launch_bounds__(512, 2)
void rnn_sync(const float* __restrict__ W_in, const f16* __restrict__ Wf,
              const f16* __restrict__ xh, char* __restrict__ X,
              unsigned* __restrict__ flags, const float* __restrict__ W_out,
              const float* __restrict__ b_out, float* __restrict__ out)
{
    __shared__ __align__(16) char sx[XFRAG];
    const int tid  = threadIdx.x;
    const int w    = tid >> 6;
    const int lane = tid & 63;
    const int b_   = lane & 15;
    const int lhi  = lane >> 4;
    const int g    = blockIdx.x & 63;
    const int p    = blockIdx.x >> 6;
    const int ot   = p * 8 + w;            // outcol tile 0..31
    const int b0   = g * 16;

    // resident W: A-frags for 16 outcols x all 512 k  (64 VGPRs)
    const f16* wbase = Wf + (size_t)(ot * 16) * 512 + lane * 8;
    f16x8 wr[16];
#pragma unroll
    for (int kk = 0; kk < 16; ++kk) wr[kk] = *(const f16x8*)(wbase + kk * 512);

    float win[4];
#pragma unroll
    for (int r = 0; r < 4; ++r) win[r] = W_in[ot * 16 + lhi * 4 + r];

    // writer offset in X (B-frag layout, derivation verified element-wise):
    //   frag kk_w = ot>>1; chunk = ((((ot&1)<<1)|(lhi>>1))<<4)|b_; +(lhi&1)*8
    const int woff = (ot >> 1) * 1024
                   + (((((ot & 1) << 1) | (lhi >> 1)) << 4) | b_) * 16
                   + (lhi & 1) * 8;

    unsigned* fl = flags + g * 16;         // words 0..3 used
    char* const Xg0 = X + g * XFRAG;               // parity 0
    char* const Xg1 = X + XHALF + g * XFRAG;       // parity 1

#pragma unroll 1
    for (int t = 0; t < T_STEPS; ++t) {
        const char* Xin  = (t & 1) ? Xg1 : Xg0;
        char*       Xout = (t & 1) ? Xg0 : Xg1;

        f32x4 acc = {0.f, 0.f, 0.f, 0.f};

        if (t > 0) {
            if (tid == 0) {
                const unsigned tt = (unsigned)t;
                for (;;) {
                    unsigned f0 = __hip_atomic_load(fl + 0, __ATOMIC_RELAXED, __HIP_MEMORY_SCOPE_AGENT);
                    unsigned f1 = __hip_atomic_load(fl + 1, __ATOMIC_RELAXED, __HIP_MEMORY_SCOPE_AGENT);
                    unsigned f2 = __hip_atomic_load(fl + 2, __ATOMIC_RELAXED, __HIP_MEMORY_SCOPE_AGENT);
                    unsigned f3 = __hip_atomic_load(fl + 3, __ATOMIC_RELAXED, __HIP_MEMORY_SCOPE_AGENT);
                    if (f0 >= tt && f1 >= tt && f2 >= tt && f3 >= tt) break;
                    __builtin_amdgcn_s_sleep(2);
                }
                __threadfence();          // acquire: invalidate L1/L2 -> fresh h
            }
            __syncthreads();
            // stage full h (16 frags x 1KB) into LDS; wave w stages 2 frags
            gload_lds16(Xin + (2 * w)     * 1024 + lane * 16, sx + (2 * w)     * 1024);
            gload_lds16(Xin + (2 * w + 1) * 1024 + lane * 16, sx + (2 * w + 1) * 1024);
            __syncthreads();              // drains vmcnt before ds_read
#pragma unroll
            for (int kk = 0; kk < 16; ++kk) {
                const f16x8 bh = *(const f16x8*)(sx + kk * 1024 + lane * 16);
                acc = MFMA16(wr[kk], bh, acc);
            }
        }

        // epilogue: inject + relu; write own 8B chunk of the group's h piece
        const float xv = (float)xh[t * 1024 + b0 + b_];
        f16x4 hv;
#pragma unroll
        for (int r = 0; r < 4; ++r)
            hv[r] = (f16)fmaxf(acc[r] + xv * win[r], 0.f);
        *(f16x4*)(Xout + woff) = hv;

        __syncthreads();                  // all waves' stores vmcnt-drained
        if (tid == 0)
            __hip_atomic_store(fl + p, (unsigned)(t + 1), __ATOMIC_RELEASE, __HIP_MEMORY_SCOPE_AGENT);
    }

    // projection by part-0 WGs: out[b,c] = h_last . W_out[c,:] + b_out[c]
    if (p == 0) {
        if (tid == 0) {
            for (;;) {
                unsigned f0 = __hip_atomic_load(fl + 0, __ATOMIC_RELAXED, __HIP_MEMORY_SCOPE_AGENT);
                unsigned f1 = __hip_atomic_load(fl + 1, __ATOMIC_RELAXED, __HIP_MEMORY_SCOPE_AGENT);
                unsigned f2 = __hip_atomic_load(fl + 2, __ATOMIC_RELAXED, __HIP_MEMORY_SCOPE_AGENT);
                unsigned f3 = __hip_atomic_load(fl + 3, __ATOMIC_RELAXED, __HIP_MEMORY_SCOPE_AGENT);
                if (f0 >= T_STEPS && f1 >= T_STEPS && f2 >= T_STEPS && f3 >= T_STEPS) break;
                __builtin_amdgcn_s_sleep(2);
            }
            __threadfence();
        }
        __syncthreads();
        if (tid < 16 * COUT) {
            const int bb = tid / COUT, c = tid % COUT;
            const char* hr = Xg0;         // parity of step 784 = 0
            float s_ = b_out[c];
            const float* wo = W_out + c * HDIM;
#pragma unroll 4
            for (int o0 = 0; o0 < HDIM; o0 += 8) {
                const int off = (o0 >> 5) * 1024 + ((((o0 >> 3) & 3) << 4) | bb) * 16;
                f16x8 hvv = *(const f16x8*)(hr + off);
#pragma unroll
                for (int jj = 0; jj < 8; ++jj)
                    s_ += (float)hvv[jj] * wo[o0 + jj];
            }
            out[(b0 + bb) * COUT + c] = s_;
        }
    }
}

// ---------------- fallback (round-6 proven kernel, f16 xt) ------------------
__global__ __launch_bounds__(512, 2)
void rnn_fb(const float* __restrict__ W_in, const f16* __restrict__ Wf,
            const float* __restrict__ W_out, const float* __restrict__ b_out,
            const f16* __restrict__ xt, float* __restrict__ out)
{
    __shared__ __align__(16) char hb[32768];
    const int tid  = threadIdx.x;
    const int w    = tid >> 6;
    const int lane = tid & 63;
    const int b    = lane & 15;
    const int lhi  = lane >> 4;
    const int b0   = blockIdx.x * 16;

    for (int i = tid; i < 4096; i += 512) ((int*)hb)[i] = 0;

    const f16* wb = Wf + (size_t)w * 32768 + lane * 8;
#define LDW(kk, n) (*(const f16x8*)(wb + ((n) * 16 + (kk)) * 512))

    f16x4 win[4];
#pragma unroll
    for (int n = 0; n < 4; ++n)
#pragma unroll
        for (int r = 0; r < 4; ++r)
            win[n][r] = (f16)W_in[w * 64 + n * 16 + lhi * 4 + r];

    char* const rb = hb + lane * 16;
    int wa[4];
#pragma unroll
    for (int n = 0; n < 4; ++n)
        wa[n] = (2 * w + (n >> 1)) * 1024
              + (((((n & 1) * 2 + (lhi >> 1)) << 4) | b) * 16)
              + (lhi & 1) * 8;

    __syncthreads();

    f16x8 r0[4], r1[4], r2[4], r3[4];
#pragma unroll
    for (int n = 0; n < 4; ++n) r0[n] = LDW(0, n);
#pragma unroll
    for (int n = 0; n < 4; ++n) r1[n] = LDW(1, n);
#pragma unroll
    for (int n = 0; n < 4; ++n) r2[n] = LDW(2, n);
#pragma unroll
    for (int n = 0; n < 4; ++n) r3[n] = LDW(3, n);

#define STEP_KK(kk, RING, nxt)                                      \
    {                                                               \
        const f16x8 bh = *(const f16x8*)(rp + (kk) * 1024);         \
        acc0 = MFMA16(RING[0], bh, acc0);                           \
        acc1 = MFMA16(RING[1], bh, acc1);                           \
        acc2 = MFMA16(RING[2], bh, acc2);                           \
        acc3 = MFMA16(RING[3], bh, acc3);                           \
        RING[0] = LDW(nxt, 0); RING[1] = LDW(nxt, 1);               \
        RING[2] = LDW(nxt, 2); RING[3] = LDW(nxt, 3);               \
    }

    int cur = 0;
#pragma unroll 1
    for (int t = 0; t < T_STEPS; ++t) {
        const float xv = (float)xt[t * 1024 + b0 + b];
        const char* rp = rb + cur;
        char* wq = hb + (cur ^ 16384);

        f32x4 acc0 = {0.f, 0.f, 0.f, 0.f};
        f32x4 acc1 = {0.f, 0.f, 0.f, 0.f};
        f32x4 acc2 = {0.f, 0.f, 0.f, 0.f};
        f32x4 acc3 = {0.f, 0.f, 0.f, 0.f};

        STEP_KK(0,  r0, 4)   STEP_KK(1,  r1, 5)
        STEP_KK(2,  r2, 6)   STEP_KK(3,  r3, 7)
        STEP_KK(4,  r0, 8)   STEP_KK(5,  r1, 9)
        STEP_KK(6,  r2, 10)  STEP_KK(7,  r3, 11)
        STEP_KK(8,  r0, 12)  STEP_KK(9,  r1, 13)
        STEP_KK(10, r2, 14)  STEP_KK(11, r3, 15)
        STEP_KK(12, r0, 0)   STEP_KK(13, r1, 1)
        STEP_KK(14, r2, 2)   STEP_KK(15, r3, 3)

        {
            f16x4 hv;
            float v;
#define EPI(n, ACC)                                                  \
            v = ACC[0] + xv * (float)win[n][0]; hv[0] = (f16)fmaxf(v, 0.f); \
            v = ACC[1] + xv * (float)win[n][1]; hv[1] = (f16)fmaxf(v, 0.f); \
            v = ACC[2] + xv * (float)win[n][2]; hv[2] = (f16)fmaxf(v, 0.f); \
            v = ACC[3] + xv * (float)win[n][3]; hv[3] = (f16)fmaxf(v, 0.f); \
            *(f16x4*)(wq + wa[n]) = hv;
            EPI(0, acc0) EPI(1, acc1) EPI(2, acc2) EPI(3, acc3)
#undef EPI
        }

        asm volatile("s_waitcnt lgkmcnt(0)\n\ts_barrier" ::: "memory");
        cur ^= 16384;
    }

    if (tid < 16 * COUT) {
        const int bb = tid / COUT, c = tid % COUT;
        const char* hr = hb + cur;
        float s_ = b_out[c];
        const float* wo = W_out + c * HDIM;
#pragma unroll 4
        for (int o0 = 0; o0 < HDIM; o0 += 8) {
            const int off = (o0 >> 5) * 1024 + (((((o0 >> 3) & 3) << 4) | bb) * 16);
            f16x8 hv = *(const f16x8*)(hr + off);
#pragma unroll
            for (int jj = 0; jj < 8; ++jj)
                s_ += (float)hv[jj] * wo[o0 + jj];
        }
        out[(b0 + bb) * COUT + c] = s_;
    }
}

extern "C" void kernel_launch(void* const* d_in, const int* in_sizes, int n_in,
                              void* d_out, int out_size, void* d_ws, size_t ws_size,
                              hipStream_t stream)
{
    (void)in_sizes; (void)n_in; (void)out_size;
    const float* x     = (const float*)d_in[0];
    const float* W_in  = (const float*)d_in[1];
    const float* W_rec = (const float*)d_in[2];
    const float* W_out = (const float*)d_in[3];
    const float* b_out = (const float*)d_in[4];
    const int*   perm  = (const int*)d_in[5];
    float* out = (float*)d_out;

    f16*      Wf    = (f16*)d_ws;
    f16*      xhp   = (f16*)((char*)d_ws + XT_OFF);
    char*     X     = (char*)d_ws + X_OFF;
    unsigned* flags = (unsigned*)((char*)d_ws + FL_OFF);

    cvt_w<<<dim3(128), dim3(256), 0, stream>>>(W_rec, Wf);
    permute_x<<<dim3(T_STEPS * 1024 / 256), dim3(256), 0, stream>>>(x, perm, xhp);

    if (ws_size >= WS_NEED) {
        hipMemsetAsync(flags, 0, FL_BYTES, stream);
        rnn_sync<<<dim3(256), dim3(512), 0, stream>>>(W_in, Wf, xhp, X, flags,
                                                      W_out, b_out, out);
    } else {
        rnn_fb<<<dim3(64), dim3(512), 0, stream>>>(W_in, Wf, W_out, b_out, xhp, out);
    }
}

// Round 8
// 1651.469 us; speedup vs baseline: 4.5242x; 4.5242x over previous
//
#include <hip/hip_runtime.h>

typedef _Float16 f16;
typedef __attribute__((ext_vector_type(8))) _Float16 f16x8;
typedef __attribute__((ext_vector_type(4))) _Float16 f16x4;
typedef __attribute__((ext_vector_type(4))) float f32x4;
typedef unsigned long long u64;

#define T_STEPS 784
#define HDIM    512
#define COUT    10
#define NGROUP  64
#define XFRAG   16384                     // bytes per group per parity (16 frags x 1KB)
#define XHALF   (NGROUP * XFRAG)

#define WF_BYTES (512 * 1024)
#define XT_OFF   WF_BYTES
#define XT_BYTES (T_STEPS * 1024 * 2)     // f16 xh
#define X_OFF    (XT_OFF + XT_BYTES)
#define X_BYTES  (2 * XHALF)
#define FL_OFF   (X_OFF + X_BYTES)
#define FL_BYTES (NGROUP * 64)
#define WS_NEED  ((size_t)(FL_OFF + FL_BYTES))

#define MFMA16(a, b, c) __builtin_amdgcn_mfma_f32_16x16x32_f16((a), (b), (c), 0, 0, 0)

// LLC-coherent (L1+L2-bypassing) accesses: system-scope relaxed atomics.
// No buffer_inv / buffer_wbl2 is emitted for relaxed -> L2 stays warm.
__device__ __forceinline__ u64 llc_ld64(const void* p) {
    return __hip_atomic_load((const u64*)p, __ATOMIC_RELAXED, __HIP_MEMORY_SCOPE_SYSTEM);
}
__device__ __forceinline__ void llc_st64(void* p, u64 v) {
    __hip_atomic_store((u64*)p, v, __ATOMIC_RELAXED, __HIP_MEMORY_SCOPE_SYSTEM);
}
__device__ __forceinline__ unsigned llc_ld32(const void* p) {
    return __hip_atomic_load((const unsigned*)p, __ATOMIC_RELAXED, __HIP_MEMORY_SCOPE_SYSTEM);
}
__device__ __forceinline__ void llc_st32(void* p, unsigned v) {
    __hip_atomic_store((unsigned*)p, v, __ATOMIC_RELAXED, __HIP_MEMORY_SCOPE_SYSTEM);
}

// W_rec f32 -> fp16, frag-major: frag f = o_tile*16+kk:
//   Wf[f*512 + lane*8 + j] = W_rec[o_tile*16+(lane&15)][kk*32+(lane>>4)*8+j]
__global__ void cvt_w(const float* __restrict__ W, f16* __restrict__ Wf) {
    const int c  = blockIdx.x * 256 + threadIdx.x;
    const int l  = c & 63;
    const int kk = (c >> 6) & 15;
    const int ot = c >> 10;
    const int row = ot * 16 + (l & 15);
    const int col = kk * 32 + (l >> 4) * 8;
    const float* s = W + row * HDIM + col;
    f16* d = Wf + (size_t)c * 8;
#pragma unroll
    for (int j = 0; j < 8; ++j) d[j] = (f16)s[j];
}

// xh[t][b] = (f16) x[b][perm[t]]
__global__ void permute_x(const float* __restrict__ x, const int* __restrict__ perm,
                          f16* __restrict__ xh) {
    const int i = blockIdx.x * 256 + threadIdx.x;
    const int t = i >> 10, b = i & 1023;
    xh[i] = (f16)x[b * T_STEPS + perm[t]];
}

__global__ void reset_flags(unsigned* __restrict__ flags) {
    flags[blockIdx.x * 256 + threadIdx.x] = 0;   // kernel-boundary flush -> visible
}

// ---- main: 4-CU groups, register-resident W, LLC h-exchange ----------------
// 256 WGs x 512 thr, 1 WG/CU. WG = (group g = bid&63, part p = bid>>6).
// Group owns 16 batch rows; part p owns outcols [p*128, p*128+128). Each wave
// holds its 16-outcol W A-frags resident in 64 VGPRs (opacity-fenced).
// Per step: spin on 4 flags (LLC), stage 16KB h LLC->LDS, 16 ds_read_b128 +
// 16 MFMA, write own 4KB piece to LLC, vmcnt(0), release flag. No L2 flushes.
__global__ __launch_bounds__(512, 2)
void rnn_sync(const float* __restrict__ W_in, const f16* __restrict__ Wf,
              const f16* __restrict__ xh, char* __restrict__ X,
              unsigned* __restrict__ flags, const float* __restrict__ W_out,
              const float* __restrict__ b_out, float* __restrict__ out)
{
    __shared__ __align__(16) char sx[XFRAG];
    const int tid  = threadIdx.x;
    const int w    = tid >> 6;
    const int lane = tid & 63;
    const int b_   = lane & 15;
    const int lhi  = lane >> 4;
    const int g    = blockIdx.x & 63;
    const int p    = blockIdx.x >> 6;
    const int ot   = p * 8 + w;            // outcol tile 0..31
    const int b0   = g * 16;

    // resident W: A-frags for 16 outcols x all 512 k (64 VGPRs), pinned
    const f16* wbase = Wf + (size_t)(ot * 16) * 512 + lane * 8;
    f16x8 wr[16];
#pragma unroll
    for (int kk = 0; kk < 16; ++kk) wr[kk] = *(const f16x8*)(wbase + kk * 512);
#pragma unroll
    for (int i = 0; i < 16; ++i) asm volatile("" : "+v"(wr[i]));

    float win[4];
#pragma unroll
    for (int r = 0; r < 4; ++r) win[r] = W_in[ot * 16 + lhi * 4 + r];

    // writer offset in X (B-frag layout; verified in rounds 6/7):
    const int woff = (ot >> 1) * 1024
                   + (((((ot & 1) << 1) | (lhi >> 1)) << 4) | b_) * 16
                   + (lhi & 1) * 8;

    unsigned* fl = flags + g * 16;         // words 0..3 used
    char* const Xg0 = X + g * XFRAG;               // parity 0
    char* const Xg1 = X + XHALF + g * XFRAG;       // parity 1

    // staging addresses: wave w copies bytes [w*2048, w*2048+2048) (frags 2w,2w+1)
    const int soff = w * 2048 + lane * 8;

#pragma unroll 1
    for (int t = 0; t < T_STEPS; ++t) {
        const char* Xin  = (t & 1) ? Xg1 : Xg0;
        char*       Xout = (t & 1) ? Xg0 : Xg1;

        f32x4 acc = {0.f, 0.f, 0.f, 0.f};

        if (t > 0) {
            if (tid == 0) {
                const unsigned tt = (unsigned)t;
                for (;;) {
                    unsigned f0 = llc_ld32(fl + 0);
                    unsigned f1 = llc_ld32(fl + 1);
                    unsigned f2 = llc_ld32(fl + 2);
                    unsigned f3 = llc_ld32(fl + 3);
                    if (f0 >= tt && f1 >= tt && f2 >= tt && f3 >= tt) break;
                    __builtin_amdgcn_s_sleep(2);
                }
            }
            __syncthreads();
            // stage 16KB h from LLC into LDS (8B/lane x 4, stride 512B)
            {
                u64 v0 = llc_ld64(Xin + soff);
                u64 v1 = llc_ld64(Xin + soff + 512);
                u64 v2 = llc_ld64(Xin + soff + 1024);
                u64 v3 = llc_ld64(Xin + soff + 1536);
                u64* dst = (u64*)(sx + soff);
                dst[0] = v0; dst[64] = v1; dst[128] = v2; dst[192] = v3;
            }
            __syncthreads();
#pragma unroll
            for (int kk = 0; kk < 16; ++kk) {
                const f16x8 bh = *(const f16x8*)(sx + kk * 1024 + lane * 16);
                acc = MFMA16(wr[kk], bh, acc);
            }
        }

        // epilogue: inject + relu; write own 8B chunk to LLC
        const float xv = (float)xh[t * 1024 + b0 + b_];
        f16x4 hv;
#pragma unroll
        for (int r = 0; r < 4; ++r)
            hv[r] = (f16)fmaxf(acc[r] + xv * win[r], 0.f);
        llc_st64(Xout + woff, *(const u64*)&hv);

        asm volatile("s_waitcnt vmcnt(0)" ::: "memory");
        __syncthreads();                  // all waves' LLC stores complete
        if (tid == 0)
            llc_st32(fl + p, (unsigned)(t + 1));
    }

    // projection by part-0 WGs: out[b,c] = h_last . W_out[c,:] + b_out[c]
    if (p == 0) {
        if (tid == 0) {
            for (;;) {
                unsigned f0 = llc_ld32(fl + 0);
                unsigned f1 = llc_ld32(fl + 1);
                unsigned f2 = llc_ld32(fl + 2);
                unsigned f3 = llc_ld32(fl + 3);
                if (f0 >= T_STEPS && f1 >= T_STEPS && f2 >= T_STEPS && f3 >= T_STEPS) break;
                __builtin_amdgcn_s_sleep(2);
            }
        }
        __syncthreads();
        // stage final h (parity 0) into LDS via LLC loads
        {
            u64 v0 = llc_ld64(Xg0 + soff);
            u64 v1 = llc_ld64(Xg0 + soff + 512);
            u64 v2 = llc_ld64(Xg0 + soff + 1024);
            u64 v3 = llc_ld64(Xg0 + soff + 1536);
            u64* dst = (u64*)(sx + soff);
            dst[0] = v0; dst[64] = v1; dst[128] = v2; dst[192] = v3;
        }
        __syncthreads();
        if (tid < 16 * COUT) {
            const int bb = tid / COUT, c = tid % COUT;
            float s_ = b_out[c];
            const float* wo = W_out + c * HDIM;
#pragma unroll 4
            for (int o0 = 0; o0 < HDIM; o0 += 8) {
                const int off = (o0 >> 5) * 1024 + ((((o0 >> 3) & 3) << 4) | bb) * 16;
                f16x8 hvv = *(const f16x8*)(sx + off);
#pragma unroll
                for (int jj = 0; jj < 8; ++jj)
                    s_ += (float)hvv[jj] * wo[o0 + jj];
            }
            out[(b0 + bb) * COUT + c] = s_;
        }
    }
}

// ---- fallback (round-6 proven kernel, f16 xt) ------------------------------
__global__ __launch_bounds__(512, 2)
void rnn_fb(const float* __restrict__ W_in, const f16* __restrict__ Wf,
            const float* __restrict__ W_out, const float* __restrict__ b_out,
            const f16* __restrict__ xt, float* __restrict__ out)
{
    __shared__ __align__(16) char hb[32768];
    const int tid  = threadIdx.x;
    const int w    = tid >> 6;
    const int lane = tid & 63;
    const int b    = lane & 15;
    const int lhi  = lane >> 4;
    const int b0   = blockIdx.x * 16;

    for (int i = tid; i < 4096; i += 512) ((int*)hb)[i] = 0;

    const f16* wb = Wf + (size_t)w * 64 * 512 + lane * 8;
#define LDW(kk, n) (*(const f16x8*)(wb + ((n) * 16 + (kk)) * 512))

    f16x4 win[4];
#pragma unroll
    for (int n = 0; n < 4; ++n)
#pragma unroll
        for (int r = 0; r < 4; ++r)
            win[n][r] = (f16)W_in[w * 64 + n * 16 + lhi * 4 + r];

    char* const rb = hb + lane * 16;
    int wa[4];
#pragma unroll
    for (int n = 0; n < 4; ++n)
        wa[n] = (2 * w + (n >> 1)) * 1024
              + (((((n & 1) * 2 + (lhi >> 1)) << 4) | b) * 16)
              + (lhi & 1) * 8;

    __syncthreads();

    f16x8 r0[4], r1[4], r2[4], r3[4];
#pragma unroll
    for (int n = 0; n < 4; ++n) r0[n] = LDW(0, n);
#pragma unroll
    for (int n = 0; n < 4; ++n) r1[n] = LDW(1, n);
#pragma unroll
    for (int n = 0; n < 4; ++n) r2[n] = LDW(2, n);
#pragma unroll
    for (int n = 0; n < 4; ++n) r3[n] = LDW(3, n);

#define STEP_KK(kk, RING, nxt)                                      \
    {                                                               \
        const f16x8 bh = *(const f16x8*)(rp + (kk) * 1024);         \
        acc0 = MFMA16(RING[0], bh, acc0);                           \
        acc1 = MFMA16(RING[1], bh, acc1);                           \
        acc2 = MFMA16(RING[2], bh, acc2);                           \
        acc3 = MFMA16(RING[3], bh, acc3);                           \
        RING[0] = LDW(nxt, 0); RING[1] = LDW(nxt, 1);               \
        RING[2] = LDW(nxt, 2); RING[3] = LDW(nxt, 3);               \
    }

    int cur = 0;
#pragma unroll 1
    for (int t = 0; t < T_STEPS; ++t) {
        const float xv = (float)xt[t * 1024 + b0 + b];
        const char* rp = rb + cur;
        char* wq = hb + (cur ^ 16384);

        f32x4 acc0 = {0.f, 0.f, 0.f, 0.f};
        f32x4 acc1 = {0.f, 0.f, 0.f, 0.f};
        f32x4 acc2 = {0.f, 0.f, 0.f, 0.f};
        f32x4 acc3 = {0.f, 0.f, 0.f, 0.f};

        STEP_KK(0,  r0, 4)   STEP_KK(1,  r1, 5)
        STEP_KK(2,  r2, 6)   STEP_KK(3,  r3, 7)
        STEP_KK(4,  r0, 8)   STEP_KK(5,  r1, 9)
        STEP_KK(6,  r2, 10)  STEP_KK(7,  r3, 11)
        STEP_KK(8,  r0, 12)  STEP_KK(9,  r1, 13)
        STEP_KK(10, r2, 14)  STEP_KK(11, r3, 15)
        STEP_KK(12, r0, 0)   STEP_KK(13, r1, 1)
        STEP_KK(14, r2, 2)   STEP_KK(15, r3, 3)

        {
            f16x4 hv;
            float v;
#define EPI(n, ACC)                                                  \
            v = ACC[0] + xv * (float)win[n][0]; hv[0] = (f16)fmaxf(v, 0.f); \
            v = ACC[1] + xv * (float)win[n][1]; hv[1] = (f16)fmaxf(v, 0.f); \
            v = ACC[2] + xv * (float)win[n][2]; hv[2] = (f16)fmaxf(v, 0.f); \
            v = ACC[3] + xv * (float)win[n][3]; hv[3] = (f16)fmaxf(v, 0.f); \
            *(f16x4*)(wq + wa[n]) = hv;
            EPI(0, acc0) EPI(1, acc1) EPI(2, acc2) EPI(3, acc3)
#undef EPI
        }

        asm volatile("s_waitcnt lgkmcnt(0)\n\ts_barrier" ::: "memory");
        cur ^= 16384;
    }

    if (tid < 16 * COUT) {
        const int bb = tid / COUT, c = tid % COUT;
        const char* hr = hb + cur;
        float s_ = b_out[c];
        const float* wo = W_out + c * HDIM;
#pragma unroll 4
        for (int o0 = 0; o0 < HDIM; o0 += 8) {
            const int off = (o0 >> 5) * 1024 + (((((o0 >> 3) & 3) << 4) | bb) * 16);
            f16x8 hv = *(const f16x8*)(hr + off);
#pragma unroll
            for (int jj = 0; jj < 8; ++jj)
                s_ += (float)hv[jj] * wo[o0 + jj];
        }
        out[(b0 + bb) * COUT + c] = s_;
    }
}

extern "C" void kernel_launch(void* const* d_in, const int* in_sizes, int n_in,
                              void* d_out, int out_size, void* d_ws, size_t ws_size,
                              hipStream_t stream)
{
    (void)in_sizes; (void)n_in; (void)out_size;
    const float* x     = (const float*)d_in[0];
    const float* W_in  = (const float*)d_in[1];
    const float* W_rec = (const float*)d_in[2];
    const float* W_out = (const float*)d_in[3];
    const float* b_out = (const float*)d_in[4];
    const int*   perm  = (const int*)d_in[5];
    float* out = (float*)d_out;

    f16*      Wf    = (f16*)d_ws;
    f16*      xhp   = (f16*)((char*)d_ws + XT_OFF);
    char*     X     = (char*)d_ws + X_OFF;
    unsigned* flags = (unsigned*)((char*)d_ws + FL_OFF);

    cvt_w<<<dim3(128), dim3(256), 0, stream>>>(W_rec, Wf);
    permute_x<<<dim3(T_STEPS * 1024 / 256), dim3(256), 0, stream>>>(x, perm, xhp);

    if (ws_size >= WS_NEED) {
        reset_flags<<<dim3(FL_BYTES / 4 / 256), dim3(256), 0, stream>>>(flags);
        rnn_sync<<<dim3(256), dim3(512), 0, stream>>>(W_in, Wf, xhp, X, flags,
                                                      W_out, b_out, out);
    } else {
        rnn_fb<<<dim3(64), dim3(512), 0, stream>>>(W_in, Wf, W_out, b_out, xhp, out);
    }
}

// Round 10
// 1527.700 us; speedup vs baseline: 4.8907x; 1.0810x over previous
//
#include <hip/hip_runtime.h>

typedef _Float16 f16;
typedef __attribute__((ext_vector_type(8))) _Float16 f16x8;
typedef __attribute__((ext_vector_type(4))) _Float16 f16x4;
typedef __attribute__((ext_vector_type(4))) float f32x4;
typedef __attribute__((ext_vector_type(4))) int i32x4;
typedef unsigned long long u64;

#define T_STEPS 784
#define HDIM    512
#define COUT    10
#define NGROUP  64
#define NSLOT   2
#define XSLOT   32768                        // 2048 chunks x 16B per group per slot

#define WF_BYTES (512 * 1024)
#define XH_OFF   WF_BYTES
#define XH_BYTES (T_STEPS * 1024 * 2)        // f16 xh
#define X_OFF    (XH_OFF + XH_BYTES)
#define X_BYTES  (NGROUP * NSLOT * XSLOT)    // 4 MB
#define WS_NEED  ((size_t)(X_OFF + X_BYTES)) // ~6.03 MB

#define MFMA16(a, b, c) __builtin_amdgcn_mfma_f32_16x16x32_f16((a), (b), (c), 0, 0, 0)
#define BAR_LGKM() asm volatile("s_waitcnt lgkmcnt(0)\n\ts_barrier" ::: "memory")

// W_rec f32 -> fp16, frag-major: frag f = ot*16+kk (ot = outcol/16):
//   Wf[f*512 + lane*8 + j] = W_rec[ot*16+(lane&15)][kk*32+(lane>>4)*8+j]
__global__ void cvt_w(const float* __restrict__ W, f16* __restrict__ Wf) {
    const int c  = blockIdx.x * 256 + threadIdx.x;
    const int l  = c & 63;
    const int kk = (c >> 6) & 15;
    const int ot = c >> 10;
    const int row = ot * 16 + (l & 15);
    const int col = kk * 32 + (l >> 4) * 8;
    const float* s = W + row * HDIM + col;
    f16* d = Wf + (size_t)c * 8;
#pragma unroll
    for (int j = 0; j < 8; ++j) d[j] = (f16)s[j];
}

// xh[t][b] = (f16) x[b][perm[t]]
__global__ void permute_x(const float* __restrict__ x, const int* __restrict__ perm,
                          f16* __restrict__ xh) {
    const int i = blockIdx.x * 256 + threadIdx.x;
    const int t = i >> 10, b = i & 1023;
    xh[i] = (f16)x[b * T_STEPS + perm[t]];
}

// zero the exchange region every launch (tags must start at 0 per replay)
__global__ void reset_x(i32x4* __restrict__ X) {
    const int i = blockIdx.x * 256 + threadIdx.x;
    const i32x4 z = {0, 0, 0, 0};
#pragma unroll
    for (int k = 0; k < 4; ++k) X[i + k * 65536] = z;
}

// ---- stage: batched 8-chunk poll (one vmcnt wait) + LDS scatter ------------
#define PUTC(i, V) *(u64*)(SX + dst[i]) = ((u64)(unsigned)(V)[0]) | (((u64)(unsigned)(V)[1]) << 32);
#define POLL8_STAGE(SBASE, TG)                                               \
    {                                                                        \
        const char* q0 = (SBASE);                                            \
        const char* q1 = (SBASE) + 4096;  const char* q2 = (SBASE) + 8192;   \
        const char* q3 = (SBASE) + 12288; const char* q4 = (SBASE) + 16384;  \
        const char* q5 = (SBASE) + 20480; const char* q6 = (SBASE) + 24576;  \
        const char* q7 = (SBASE) + 28672;                                    \
        i32x4 v0, v1, v2, v3, v4, v5, v6, v7;                                \
        for (;;) {                                                           \
            asm volatile(                                                    \
                "global_load_dwordx4 %0, %8, off sc0 sc1\n\t"               \
                "global_load_dwordx4 %1, %9, off sc0 sc1\n\t"               \
                "global_load_dwordx4 %2, %10, off sc0 sc1\n\t"              \
                "global_load_dwordx4 %3, %11, off sc0 sc1\n\t"              \
                "global_load_dwordx4 %4, %12, off sc0 sc1\n\t"              \
                "global_load_dwordx4 %5, %13, off sc0 sc1\n\t"              \
                "global_load_dwordx4 %6, %14, off sc0 sc1\n\t"              \
                "global_load_dwordx4 %7, %15, off sc0 sc1\n\t"              \
                "s_waitcnt vmcnt(0)"                                         \
                : "=&v"(v0), "=&v"(v1), "=&v"(v2), "=&v"(v3),                \
                  "=&v"(v4), "=&v"(v5), "=&v"(v6), "=&v"(v7)                 \
                : "v"(q0), "v"(q1), "v"(q2), "v"(q3),                        \
                  "v"(q4), "v"(q5), "v"(q6), "v"(q7)                         \
                : "memory");                                                 \
            if (v0[2] == (TG) && v1[2] == (TG) && v2[2] == (TG) &&           \
                v3[2] == (TG) && v4[2] == (TG) && v5[2] == (TG) &&           \
                v6[2] == (TG) && v7[2] == (TG)) break;                       \
            __builtin_amdgcn_s_sleep(1);                                     \
        }                                                                    \
        PUTC(0, v0) PUTC(1, v1) PUTC(2, v2) PUTC(3, v3)                      \
        PUTC(4, v4) PUTC(5, v5) PUTC(6, v6) PUTC(7, v7)                      \
    }

// ---- main: 4-CU groups, W in LDS, tag-in-data LLC exchange -----------------
// 256 WGs x 256 thr (4 waves), 1 WG/CU (128 KB LDS). group g = bid&63,
// part p = bid>>6 owns outcols [p*128, p*128+128); wave w owns otiles
// p*8+2w, p*8+2w+1. W A-frags kk0..13 in LDS (112 KB), kk14..15 in regs.
// Per step: poll 8 chunks/thread (tag==t) -> LDS, barrier, 32 MFMA/wave,
// epilogue packs {h(8B), tag t+1} into one 16B sc0sc1 store. No flags,
// no atomics, no drains; writer pacing guarantees NSLOT=2 is race-free.
__global__ __launch_bounds__(256)
void rnn_tag(const float* __restrict__ W_in, const f16* __restrict__ Wf,
             const f16* __restrict__ xh, char* __restrict__ X,
             const float* __restrict__ W_out, const float* __restrict__ b_out,
             float* __restrict__ out)
{
    __shared__ __align__(16) char lds[131072];   // [0,112K): W frags; [112K,128K): SX
    char* const SX = lds + 114688;

    const int tid  = threadIdx.x;
    const int w    = tid >> 6;
    const int lane = tid & 63;
    const int b_   = lane & 15;
    const int lhi  = lane >> 4;
    const int g    = blockIdx.x & 63;
    const int p    = blockIdx.x >> 6;
    const int ot0  = p * 8 + w * 2, ot1 = ot0 + 1;
    const int b0   = g * 16;
    char* const Xg = X + (size_t)g * (NSLOT * XSLOT);

    // fill W LDS (kk 0..13 for both otiles)
#pragma unroll
    for (int j = 0; j < 2; ++j) {
        const int ot = ot0 + j;
#pragma unroll
        for (int kk = 0; kk < 14; ++kk)
            *(f16x8*)(lds + (((w * 2 + j) * 14 + kk) * 1024) + lane * 16)
                = *(const f16x8*)(Wf + ((size_t)(ot * 16 + kk) * 64 + lane) * 8);
    }
    // streamed kk 14,15 held in registers (loop-invariant)
    const f16x8 a14_0 = *(const f16x8*)(Wf + ((size_t)(ot0 * 16 + 14) * 64 + lane) * 8);
    const f16x8 a15_0 = *(const f16x8*)(Wf + ((size_t)(ot0 * 16 + 15) * 64 + lane) * 8);
    const f16x8 a14_1 = *(const f16x8*)(Wf + ((size_t)(ot1 * 16 + 14) * 64 + lane) * 8);
    const f16x8 a15_1 = *(const f16x8*)(Wf + ((size_t)(ot1 * 16 + 15) * 64 + lane) * 8);

    float win0[4], win1[4];
#pragma unroll
    for (int r = 0; r < 4; ++r) {
        win0[r] = W_in[ot0 * 16 + lhi * 4 + r];
        win1[r] = W_in[ot1 * 16 + lhi * 4 + r];
    }

    // stage destinations (chunk c -> B-frag byte offset; layout proven r6-r8)
    int dst[8];
#pragma unroll
    for (int i = 0; i < 8; ++i) {
        const int c = tid + 256 * i;
        const int ot = c >> 6, lh = (c >> 4) & 3, bb = c & 15;
        dst[i] = (ot >> 1) * 1024 + ((ot & 1) * 2 + (lh >> 1)) * 256 + bb * 16 + (lh & 1) * 8;
    }
    // writer chunk byte offsets
    const int wc0 = (ot0 * 64 + lhi * 16 + b_) * 16;
    const int wc1 = (ot1 * 64 + lhi * 16 + b_) * 16;

    __syncthreads();   // W LDS ready

#pragma unroll 1
    for (int t = 0; t < T_STEPS; ++t) {
        f32x4 acc0 = {0.f, 0.f, 0.f, 0.f};
        f32x4 acc1 = {0.f, 0.f, 0.f, 0.f};

        if (t > 0) {
            const char* sb = Xg + ((t - 1) & 1) * XSLOT + tid * 16;
            POLL8_STAGE(sb, t)
            BAR_LGKM();                       // SX staged; stores fly free
#pragma unroll
            for (int kk = 0; kk < 14; ++kk) {
                const f16x8 bh = *(const f16x8*)(SX + kk * 1024 + lane * 16);
                const f16x8 a0 = *(const f16x8*)(lds + (((w * 2 + 0) * 14 + kk) * 1024) + lane * 16);
                const f16x8 a1 = *(const f16x8*)(lds + (((w * 2 + 1) * 14 + kk) * 1024) + lane * 16);
                acc0 = MFMA16(a0, bh, acc0);
                acc1 = MFMA16(a1, bh, acc1);
            }
            const f16x8 bh14 = *(const f16x8*)(SX + 14 * 1024 + lane * 16);
            const f16x8 bh15 = *(const f16x8*)(SX + 15 * 1024 + lane * 16);
            acc0 = MFMA16(a14_0, bh14, acc0);
            acc1 = MFMA16(a14_1, bh14, acc1);
            acc0 = MFMA16(a15_0, bh15, acc0);
            acc1 = MFMA16(a15_1, bh15, acc1);
        }

        // epilogue: inject + relu, pack {h, tag} and store 16B (no drain)
        const float xv = (float)xh[t * 1024 + b0 + b_];
        union { f16x4 h; int d[2]; } u0, u1;
#pragma unroll
        for (int r = 0; r < 4; ++r) {
            u0.h[r] = (f16)fmaxf(acc0[r] + xv * win0[r], 0.f);
            u1.h[r] = (f16)fmaxf(acc1[r] + xv * win1[r], 0.f);
        }
        char* Xo = Xg + (t & 1) * XSLOT;
        const i32x4 s0 = {u0.d[0], u0.d[1], t + 1, 0};
        const i32x4 s1 = {u1.d[0], u1.d[1], t + 1, 0};
        asm volatile("global_store_dwordx4 %0, %1, off sc0 sc1"
                     :: "v"(Xo + wc0), "v"(s0) : "memory");
        asm volatile("global_store_dwordx4 %0, %1, off sc0 sc1"
                     :: "v"(Xo + wc1), "v"(s1) : "memory");

        BAR_LGKM();                           // SX consumption done before next stage
    }

    // ---- projection by part-0 WGs: out[b,c] = h_last . W_out[c,:] + b_out[c]
    if (p == 0) {
        const char* sb = Xg + ((T_STEPS - 1) & 1) * XSLOT + tid * 16;
        POLL8_STAGE(sb, T_STEPS)
        __syncthreads();
        if (tid < 16 * COUT) {
            const int bb = tid / COUT, c = tid % COUT;
            float s_ = b_out[c];
            const float* wo = W_out + c * HDIM;
#pragma unroll 4
            for (int o0 = 0; o0 < HDIM; o0 += 8) {
                const int off = (o0 >> 5) * 1024 + ((((o0 >> 3) & 3) << 4) | bb) * 16;
                f16x8 hvv = *(const f16x8*)(SX + off);
#pragma unroll
                for (int jj = 0; jj < 8; ++jj)
                    s_ += (float)hvv[jj] * wo[o0 + jj];
            }
            out[(b0 + bb) * COUT + c] = s_;
        }
    }
}

// ---- fallback (round-6 proven kernel, f16 xt) ------------------------------
__global__ __launch_bounds__(512, 2)
void rnn_fb(const float* __restrict__ W_in, const f16* __restrict__ Wf,
            const float* __restrict__ W_out, const float* __restrict__ b_out,
            const f16* __restrict__ xt, float* __restrict__ out)
{
    __shared__ __align__(16) char hb[32768];
    const int tid  = threadIdx.x;
    const int w    = tid >> 6;
    const int lane = tid & 63;
    const int b    = lane & 15;
    const int lhi  = lane >> 4;
    const int b0   = blockIdx.x * 16;

    for (int i = tid; i < 4096; i += 512) ((int*)hb)[i] = 0;

    const f16* wb = Wf + (size_t)w * 64 * 512 + lane * 8;
#define LDW(kk, n) (*(const f16x8*)(wb + ((n) * 16 + (kk)) * 512))

    f16x4 win[4];
#pragma unroll
    for (int n = 0; n < 4; ++n)
#pragma unroll
        for (int r = 0; r < 4; ++r)
            win[n][r] = (f16)W_in[w * 64 + n * 16 + lhi * 4 + r];

    char* const rb = hb + lane * 16;
    int wa[4];
#pragma unroll
    for (int n = 0; n < 4; ++n)
        wa[n] = (2 * w + (n >> 1)) * 1024
              + (((((n & 1) * 2 + (lhi >> 1)) << 4) | b) * 16)
              + (lhi & 1) * 8;

    __syncthreads();

    f16x8 r0[4], r1[4], r2[4], r3[4];
#pragma unroll
    for (int n = 0; n < 4; ++n) r0[n] = LDW(0, n);
#pragma unroll
    for (int n = 0; n < 4; ++n) r1[n] = LDW(1, n);
#pragma unroll
    for (int n = 0; n < 4; ++n) r2[n] = LDW(2, n);
#pragma unroll
    for (int n = 0; n < 4; ++n) r3[n] = LDW(3, n);

#define STEP_KK(kk, RING, nxt)                                      \
    {                                                               \
        const f16x8 bh = *(const f16x8*)(rp + (kk) * 1024);         \
        acc0 = MFMA16(RING[0], bh, acc0);                           \
        acc1 = MFMA16(RING[1], bh, acc1);                           \
        acc2 = MFMA16(RING[2], bh, acc2);                           \
        acc3 = MFMA16(RING[3], bh, acc3);                           \
        RING[0] = LDW(nxt, 0); RING[1] = LDW(nxt, 1);               \
        RING[2] = LDW(nxt, 2); RING[3] = LDW(nxt, 3);               \
    }

    int cur = 0;
#pragma unroll 1
    for (int t = 0; t < T_STEPS; ++t) {
        const float xv = (float)xt[t * 1024 + b0 + b];
        const char* rp = rb + cur;
        char* wq = hb + (cur ^ 16384);

        f32x4 acc0 = {0.f, 0.f, 0.f, 0.f};
        f32x4 acc1 = {0.f, 0.f, 0.f, 0.f};
        f32x4 acc2 = {0.f, 0.f, 0.f, 0.f};
        f32x4 acc3 = {0.f, 0.f, 0.f, 0.f};

        STEP_KK(0,  r0, 4)   STEP_KK(1,  r1, 5)
        STEP_KK(2,  r2, 6)   STEP_KK(3,  r3, 7)
        STEP_KK(4,  r0, 8)   STEP_KK(5,  r1, 9)
        STEP_KK(6,  r2, 10)  STEP_KK(7,  r3, 11)
        STEP_KK(8,  r0, 12)  STEP_KK(9,  r1, 13)
        STEP_KK(10, r2, 14)  STEP_KK(11, r3, 15)
        STEP_KK(12, r0, 0)   STEP_KK(13, r1, 1)
        STEP_KK(14, r2, 2)   STEP_KK(15, r3, 3)

        {
            f16x4 hv;
            float v;
#define EPI(n, ACC)                                                  \
            v = ACC[0] + xv * (float)win[n][0]; hv[0] = (f16)fmaxf(v, 0.f); \
            v = ACC[1] + xv * (float)win[n][1]; hv[1] = (f16)fmaxf(v, 0.f); \
            v = ACC[2] + xv * (float)win[n][2]; hv[2] = (f16)fmaxf(v, 0.f); \
            v = ACC[3] + xv * (float)win[n][3]; hv[3] = (f16)fmaxf(v, 0.f); \
            *(f16x4*)(wq + wa[n]) = hv;
            EPI(0, acc0) EPI(1, acc1) EPI(2, acc2) EPI(3, acc3)
#undef EPI
        }

        asm volatile("s_waitcnt lgkmcnt(0)\n\ts_barrier" ::: "memory");
        cur ^= 16384;
    }

    if (tid < 16 * COUT) {
        const int bb = tid / COUT, c = tid % COUT;
        const char* hr = hb + cur;
        float s_ = b_out[c];
        const float* wo = W_out + c * HDIM;
#pragma unroll 4
        for (int o0 = 0; o0 < HDIM; o0 += 8) {
            const int off = (o0 >> 5) * 1024 + (((((o0 >> 3) & 3) << 4) | bb) * 16);
            f16x8 hv = *(const f16x8*)(hr + off);
#pragma unroll
            for (int jj = 0; jj < 8; ++jj)
                s_ += (float)hv[jj] * wo[o0 + jj];
        }
        out[(b0 + bb) * COUT + c] = s_;
    }
}

extern "C" void kernel_launch(void* const* d_in, const int* in_sizes, int n_in,
                              void* d_out, int out_size, void* d_ws, size_t ws_size,
                              hipStream_t stream)
{
    (void)in_sizes; (void)n_in; (void)out_size;
    const float* x     = (const float*)d_in[0];
    const float* W_in  = (const float*)d_in[1];
    const float* W_rec = (const float*)d_in[2];
    const float* W_out = (const float*)d_in[3];
    const float* b_out = (const float*)d_in[4];
    const int*   perm  = (const int*)d_in[5];
    float* out = (float*)d_out;

    f16*  Wf  = (f16*)d_ws;
    f16*  xhp = (f16*)((char*)d_ws + XH_OFF);
    char* X   = (char*)d_ws + X_OFF;

    cvt_w<<<dim3(128), dim3(256), 0, stream>>>(W_rec, Wf);
    permute_x<<<dim3(T_STEPS * 1024 / 256), dim3(256), 0, stream>>>(x, perm, xhp);

    if (ws_size >= WS_NEED) {
        reset_x<<<dim3(256), dim3(256), 0, stream>>>((i32x4*)X);
        rnn_tag<<<dim3(256), dim3(256), 0, stream>>>(W_in, Wf, xhp, X,
                                                     W_out, b_out, out);
    } else {
        rnn_fb<<<dim3(64), dim3(512), 0, stream>>>(W_in, Wf, W_out, b_out, xhp, out);
    }
}